// Round 3
// baseline (789.476 us; speedup 1.0000x reference)
//
#include <hip/hip_runtime.h>
#include <stdint.h>

#define D 128
#define TN 64

typedef __attribute__((ext_vector_type(8))) __bf16 bf16x8;
typedef __attribute__((ext_vector_type(4))) float f32x4;

// ---------------------------------------------------------------------------
// edge_index dtype detection (int64 per reference vs int32 from x64-disabled JAX)
__global__ void detect_idx(const void* ei, int* flag, int n_nodes) {
    if (blockIdx.x == 0 && threadIdx.x == 0) {
        const long long* p = (const long long*)ei;
        int is64 = 1;
        for (int i = 0; i < 64; ++i) {
            long long v = p[i];
            if (v < 0 || v >= (long long)n_nodes) { is64 = 0; break; }
        }
        *flag = is64;
    }
}

__global__ void convert_idx(const void* ei, const int* flag,
                            int* src32, int* dst32, int nE) {
    int e = blockIdx.x * blockDim.x + threadIdx.x;
    if (e >= nE) return;
    if (*flag) {
        const long long* p = (const long long*)ei;
        src32[e] = (int)p[e];
        dst32[e] = (int)p[(size_t)nE + e];
    } else {
        const int* p = (const int*)ei;
        src32[e] = p[e];
        dst32[e] = p[nE + e];
    }
}

// ---------------------------------------------------------------------------
// CSR build (by dst), reused across all 3 layers
__global__ void hist_kernel(const int* dst32, int* counts, int nE) {
    int e = blockIdx.x * blockDim.x + threadIdx.x;
    if (e < nE) atomicAdd(&counts[dst32[e]], 1);
}

__global__ void scan1(const int* counts, int* local_inc, int* bsums, int n) {
    __shared__ int s[1024];
    int i = blockIdx.x * 1024 + threadIdx.x;
    int v = (i < n) ? counts[i] : 0;
    s[threadIdx.x] = v;
    __syncthreads();
    for (int off = 1; off < 1024; off <<= 1) {
        int t = 0;
        if ((int)threadIdx.x >= off) t = s[threadIdx.x - off];
        __syncthreads();
        if ((int)threadIdx.x >= off) s[threadIdx.x] += t;
        __syncthreads();
    }
    if (i < n) local_inc[i] = s[threadIdx.x];
    if (threadIdx.x == 1023) bsums[blockIdx.x] = s[1023];
}

__global__ void scan2(int* bsums, int nb) {
    if (blockIdx.x == 0 && threadIdx.x == 0) {
        int run = 0;
        for (int i = 0; i < nb; ++i) { int v = bsums[i]; bsums[i] = run; run += v; }
    }
}

__global__ void scan3(const int* local_inc, const int* counts, const int* bsums,
                      int* offsets, int n, int nE) {
    int i = blockIdx.x * blockDim.x + threadIdx.x;
    if (i < n) offsets[i] = local_inc[i] - counts[i] + bsums[i >> 10];
    if (i == 0) offsets[n] = nE;
}

__global__ void fill_csr(const int* src32, const int* dst32, const int* offsets,
                         int* cursor, int* csr_src, int nE) {
    int e = blockIdx.x * blockDim.x + threadIdx.x;
    if (e < nE) {
        int d = dst32[e];
        int pos = offsets[d] + atomicAdd(&cursor[d], 1);
        csr_src[pos] = src32[e];
    }
}

// ---------------------------------------------------------------------------
// W preprocessing: stacked [Wl;Wr] transposed to [col][k], split bf16 hi/lo.
__global__ void build_wt(const float* __restrict__ Wa, const float* __restrict__ Wr,
                         __bf16* __restrict__ WtHi, __bf16* __restrict__ WtLo) {
    int idx = blockIdx.x * 256 + threadIdx.x;         // 3*128*256 total
    if (idx >= 3 * 128 * 256) return;
    int L = idx / (128 * 256);
    int rem = idx % (128 * 256);
    int c = rem / 256;
    int k = rem % 256;
    float v = (k < 128) ? Wa[((size_t)L * 128 + k) * 128 + c]
                        : Wr[((size_t)L * 128 + (k - 128)) * 128 + c];
    __bf16 h = (__bf16)v;
    __bf16 l = (__bf16)(v - (float)h);
    WtHi[idx] = h;
    WtLo[idx] = l;
}

// ---------------------------------------------------------------------------
// x fp32 -> bf16 hi/lo planes (once, layer-0 input)
__global__ void split_x(const float* __restrict__ x, __bf16* __restrict__ aHi,
                        __bf16* __restrict__ aLo, int total8) {
    int i = blockIdx.x * 256 + threadIdx.x;           // 8 floats per thread
    if (i >= total8) return;
    const float4* p = (const float4*)(x + (size_t)i * 8);
    float4 v0 = p[0], v1 = p[1];
    float vv[8] = {v0.x, v0.y, v0.z, v0.w, v1.x, v1.y, v1.z, v1.w};
    bf16x8 h, l;
    #pragma unroll
    for (int j = 0; j < 8; ++j) {
        __bf16 hh = (__bf16)vv[j];
        h[j] = hh;
        l[j] = (__bf16)(vv[j] - (float)hh);
    }
    *(bf16x8*)(aHi + (size_t)i * 8) = h;
    *(bf16x8*)(aLo + (size_t)i * 8) = l;
}

// ---------------------------------------------------------------------------
// mean aggregation v3: gather bf16 HI plane only (256B/row). One node per
// 16-lane group (bf16x8 = 16B/lane), 4x unrolled independent row gathers.
// fp32 accumulate; write mean as hi/lo bf16 planes.
__global__ __launch_bounds__(256) void agg_mean3(
        const __bf16* __restrict__ aHi, const int* __restrict__ csr,
        const int* __restrict__ offs, __bf16* __restrict__ mHi,
        __bf16* __restrict__ mLo, int n) {
    int node = (blockIdx.x * blockDim.x + threadIdx.x) >> 4;
    int l8 = (threadIdx.x & 15) << 3;     // bf16 offset of this lane's 8 elems
    if (node >= n) return;
    int beg = offs[node], end = offs[node + 1];
    float acc[8] = {0.f, 0.f, 0.f, 0.f, 0.f, 0.f, 0.f, 0.f};
    int i = beg;
    for (; i + 4 <= end; i += 4) {
        int s0 = csr[i], s1 = csr[i + 1], s2 = csr[i + 2], s3 = csr[i + 3];
        bf16x8 v0 = *(const bf16x8*)(aHi + (size_t)s0 * D + l8);
        bf16x8 v1 = *(const bf16x8*)(aHi + (size_t)s1 * D + l8);
        bf16x8 v2 = *(const bf16x8*)(aHi + (size_t)s2 * D + l8);
        bf16x8 v3 = *(const bf16x8*)(aHi + (size_t)s3 * D + l8);
        #pragma unroll
        for (int j = 0; j < 8; ++j)
            acc[j] += (float)v0[j] + (float)v1[j] + (float)v2[j] + (float)v3[j];
    }
    for (; i < end; ++i) {
        int s = csr[i];
        bf16x8 v = *(const bf16x8*)(aHi + (size_t)s * D + l8);
        #pragma unroll
        for (int j = 0; j < 8; ++j) acc[j] += (float)v[j];
    }
    int deg = end - beg;
    float inv = 1.0f / (float)(deg > 1 ? deg : 1);
    bf16x8 h, l;
    #pragma unroll
    for (int j = 0; j < 8; ++j) {
        float m = acc[j] * inv;
        __bf16 hh = (__bf16)m;
        h[j] = hh;
        l[j] = (__bf16)(m - (float)hh);
    }
    *(bf16x8*)(mHi + (size_t)node * D + l8) = h;
    *(bf16x8*)(mLo + (size_t)node * D + l8) = l;
}

// ---------------------------------------------------------------------------
// MFMA GEMM v3: LDS-free, barrier-free. out = [mean|act] @ [Wl;Wr] + b.
// Tile 64 nodes x 128 cols, 4 waves; wave w owns rows w*16..+16 exclusively
// (reads its own band only, writes its own band only -> in-place safe).
// A frags from mean/act hi-lo planes, B frags from L2-resident Wt planes.
// acc += hi*hi + hi*lo + lo*hi. mode 0: relu + bf16 hi/lo store; 1: fp32 out.
__global__ __launch_bounds__(256) void sage_gemm3(
        const __bf16* __restrict__ mHi, const __bf16* __restrict__ mLo,
        const __bf16* __restrict__ aHi, const __bf16* __restrict__ aLo,
        const __bf16* __restrict__ WtHi, const __bf16* __restrict__ WtLo,
        const float* __restrict__ bias,
        __bf16* __restrict__ oHi, __bf16* __restrict__ oLo,
        float* __restrict__ oF, int n, int mode) {
    int tid  = threadIdx.x;
    int wave = tid >> 6;
    int lane = tid & 63;
    int row16 = lane & 15;
    int kg    = lane >> 4;
    int node0 = blockIdx.x * TN;
    int arow  = node0 + wave * 16 + row16;
    bool valid = arow < n;

    bf16x8 zero;
    #pragma unroll
    for (int j = 0; j < 8; ++j) zero[j] = (__bf16)0.f;

    f32x4 acc[8];
    #pragma unroll
    for (int nt = 0; nt < 8; ++nt) acc[nt] = (f32x4){0.f, 0.f, 0.f, 0.f};

    #pragma unroll
    for (int half = 0; half < 2; ++half) {
        const __bf16* hi = half ? aHi : mHi;
        const __bf16* lo = half ? aLo : mLo;
        #pragma unroll
        for (int kc = 0; kc < 4; ++kc) {         // 4 x 32-k chunks per half
            int k0 = kc * 32 + kg * 8;
            bf16x8 ah = valid ? *(const bf16x8*)(hi + (size_t)arow * D + k0) : zero;
            bf16x8 al = valid ? *(const bf16x8*)(lo + (size_t)arow * D + k0) : zero;
            int ktk = half * 128 + k0;           // k in stacked-256 Wt
            #pragma unroll
            for (int nt = 0; nt < 8; ++nt) {
                int col = nt * 16 + row16;
                bf16x8 bh = *(const bf16x8*)(WtHi + (size_t)col * 256 + ktk);
                bf16x8 bl = *(const bf16x8*)(WtLo + (size_t)col * 256 + ktk);
                acc[nt] = __builtin_amdgcn_mfma_f32_16x16x32_bf16(ah, bh, acc[nt], 0, 0, 0);
                acc[nt] = __builtin_amdgcn_mfma_f32_16x16x32_bf16(ah, bl, acc[nt], 0, 0, 0);
                acc[nt] = __builtin_amdgcn_mfma_f32_16x16x32_bf16(al, bh, acc[nt], 0, 0, 0);
            }
        }
    }

    // epilogue: C/D layout col=lane&15, row=(lane>>4)*4+reg (m89-verified)
    #pragma unroll
    for (int nt = 0; nt < 8; ++nt) {
        int col = nt * 16 + row16;
        float bv = bias[col];
        #pragma unroll
        for (int j = 0; j < 4; ++j) {
            int node = node0 + wave * 16 + kg * 4 + j;
            if (node < n) {
                float v = acc[nt][j] + bv;
                if (mode == 0) {
                    v = fmaxf(v, 0.f);
                    __bf16 h = (__bf16)v;
                    __bf16 l = (__bf16)(v - (float)h);
                    oHi[(size_t)node * D + col] = h;
                    oLo[(size_t)node * D + col] = l;
                } else {
                    oF[(size_t)node * D + col] = v;
                }
            }
        }
    }
}

// ---------------------------------------------------------------------------
extern "C" void kernel_launch(void* const* d_in, const int* in_sizes, int n_in,
                              void* d_out, int out_size, void* d_ws, size_t ws_size,
                              hipStream_t stream) {
    const float* x  = (const float*)d_in[0];
    const void*  ei = d_in[1];
    const float* Wa = (const float*)d_in[2];   // [3,128,128]
    const float* Wr = (const float*)d_in[3];   // [3,128,128]
    const float* bb = (const float*)d_in[4];   // [3,128]
    float* outp = (float*)d_out;

    int n  = in_sizes[0] / D;          // 100000
    int nE = in_sizes[1] / 2;          // 1600000

    char* ws = (char*)d_ws;
    size_t off = 0;
    auto alloc = [&](size_t bytes) -> char* {
        char* p = ws + off;
        off = (off + bytes + 255) & ~(size_t)255;
        return p;
    };
    int* flag      = (int*)alloc(4);
    int* src32     = (int*)alloc((size_t)nE * 4);
    int* dst32     = (int*)alloc((size_t)nE * 4);
    int* counts    = (int*)alloc((size_t)n * 4);
    int* offsets   = (int*)alloc(((size_t)n + 1) * 4);
    int* cursor    = (int*)alloc((size_t)n * 4);
    int* local_inc = (int*)alloc((size_t)n * 4);
    int* bsums     = (int*)alloc(1024);
    int* csr_src   = (int*)alloc((size_t)nE * 4);
    __bf16* actHi  = (__bf16*)alloc((size_t)n * D * 2);
    __bf16* actLo  = (__bf16*)alloc((size_t)n * D * 2);
    __bf16* mHi    = (__bf16*)alloc((size_t)n * D * 2);
    __bf16* mLo    = (__bf16*)alloc((size_t)n * D * 2);
    __bf16* WtHi   = (__bf16*)alloc((size_t)3 * 128 * 256 * 2);
    __bf16* WtLo   = (__bf16*)alloc((size_t)3 * 128 * 256 * 2);
    (void)ws_size; (void)n_in; (void)out_size;

    const int B = 256;
    int ge = (nE + B - 1) / B;
    int nb = (n + 1023) / 1024;

    // 1) index probe + conversion + W transpose/split + x split
    hipLaunchKernelGGL(detect_idx, dim3(1), dim3(64), 0, stream, ei, flag, n);
    hipLaunchKernelGGL(convert_idx, dim3(ge), dim3(B), 0, stream,
                       ei, flag, src32, dst32, nE);
    hipLaunchKernelGGL(build_wt, dim3(384), dim3(256), 0, stream, Wa, Wr, WtHi, WtLo);
    int total8 = n * D / 8;
    hipLaunchKernelGGL(split_x, dim3((total8 + 255) / 256), dim3(256), 0, stream,
                       x, actHi, actLo, total8);

    // 2) CSR build
    hipMemsetAsync(counts, 0, (size_t)n * 4, stream);
    hipMemsetAsync(cursor, 0, (size_t)n * 4, stream);
    hipLaunchKernelGGL(hist_kernel, dim3(ge), dim3(B), 0, stream, dst32, counts, nE);
    hipLaunchKernelGGL(scan1, dim3(nb), dim3(1024), 0, stream,
                       counts, local_inc, bsums, n);
    hipLaunchKernelGGL(scan2, dim3(1), dim3(64), 0, stream, bsums, nb);
    hipLaunchKernelGGL(scan3, dim3((n + B - 1) / B), dim3(B), 0, stream,
                       local_inc, counts, bsums, offsets, n, nE);
    hipLaunchKernelGGL(fill_csr, dim3(ge), dim3(B), 0, stream,
                       src32, dst32, offsets, cursor, csr_src, nE);

    // 3) layers (act planes updated in-place: wave-exclusive 16-row bands)
    int agg_blocks  = (n * 16 + B - 1) / B;        // 16 lanes per node
    int gemm_blocks = (n + TN - 1) / TN;
    const int WSTRIDE = 128 * 256;

    // layer 0 (ReLU)
    hipLaunchKernelGGL(agg_mean3, dim3(agg_blocks), dim3(B), 0, stream,
                       actHi, csr_src, offsets, mHi, mLo, n);
    hipLaunchKernelGGL(sage_gemm3, dim3(gemm_blocks), dim3(B), 0, stream,
                       mHi, mLo, actHi, actLo, WtHi + 0 * WSTRIDE, WtLo + 0 * WSTRIDE,
                       bb + 0 * D, actHi, actLo, outp, n, 0);

    // layer 1 (ReLU)
    hipLaunchKernelGGL(agg_mean3, dim3(agg_blocks), dim3(B), 0, stream,
                       actHi, csr_src, offsets, mHi, mLo, n);
    hipLaunchKernelGGL(sage_gemm3, dim3(gemm_blocks), dim3(B), 0, stream,
                       mHi, mLo, actHi, actLo, WtHi + 1 * WSTRIDE, WtLo + 1 * WSTRIDE,
                       bb + 1 * D, actHi, actLo, outp, n, 0);

    // layer 2 (no ReLU, fp32 out)
    hipLaunchKernelGGL(agg_mean3, dim3(agg_blocks), dim3(B), 0, stream,
                       actHi, csr_src, offsets, mHi, mLo, n);
    hipLaunchKernelGGL(sage_gemm3, dim3(gemm_blocks), dim3(B), 0, stream,
                       mHi, mLo, actHi, actLo, WtHi + 2 * WSTRIDE, WtLo + 2 * WSTRIDE,
                       bb + 2 * D, actHi, actLo, outp, n, 1);
}